// Round 6
// baseline (314.245 us; speedup 1.0000x reference)
//
#include <hip/hip_runtime.h>
#include <hip/hip_bf16.h>

#define BB 256
#define PP 48
#define NN 64
#define EPSBN 1e-5f

typedef __attribute__((ext_vector_type(8))) short bf16x8;
typedef __attribute__((ext_vector_type(4))) float f32x4;

// ---- LDS regions (ushort offsets), total 81920 ushorts = 163840 B (160 KiB) ----
#define BIGO 0       // 32768: fr1R/[+16384]fr1S -> fr2 [128][256]   | N: fo1 [256][128] -> fo2 [128][256]
#define S1SO 32768   // 16384: S1S [64][256]                          | N: act1N [64][256]
#define S1RO 49152   // 16384: S1R [64][256]; cols 0..63 -> ebar      | N: fo3 [64][128]
#define A2WO 65536   // 16384: phase E: 8 waves x 2048 private act2   | N: act2N [64][128]
#define XNT2 73728   //  4096: xnT [64][64] (clobbered by waves 4..7 a2w in phase E; restaged)
#define REDO 77824   //  4096: phase N red/h1/h2 (floats)
#define LDSE 81920

union U8 { bf16x8 v; unsigned u[4]; };

__device__ __forceinline__ unsigned pku(float a, float b) {
    union { __hip_bfloat162 h; unsigned u; } cv;
    cv.h = __float22bfloat162_rn(make_float2(a, b));
    return cv.u;
}
__device__ __forceinline__ ushort f2b(float f) {
    union { float f; unsigned u; } a; a.f = f;
    unsigned u = a.u + 0x7FFFu + ((a.u >> 16) & 1u);
    return (ushort)(u >> 16);
}
__device__ __forceinline__ float loF(unsigned u) { union { unsigned x; float f; } c; c.x = u << 16; return c.f; }
__device__ __forceinline__ float hiF(unsigned u) { union { unsigned x; float f; } c; c.x = u & 0xffff0000u; return c.f; }

__device__ __forceinline__ int sidx(int row, int k, int kpad) {
    return row * kpad + ((((k >> 3) ^ (row & 7)) << 3) | (k & 7));
}
__device__ __forceinline__ bf16x8 ldfrag(const ushort* buf, int row, int k, int kpad) {
    return *(const bf16x8*)(buf + row * kpad + (((k >> 3) ^ (row & 7)) << 3));
}
__device__ __forceinline__ f32x4 MFMA(bf16x8 a, bf16x8 b, f32x4 c) {
    return __builtin_amdgcn_mfma_f32_16x16x32_bf16(a, b, c, 0, 0, 0);
}
__device__ __forceinline__ void stAct(ushort* buf, int row, int c0, int kpad, f32x4 a, float4 bi) {
    uint2 o;
    o.x = pku(fmaxf(a[0] + bi.x, 0.f), fmaxf(a[1] + bi.y, 0.f));
    o.y = pku(fmaxf(a[2] + bi.z, 0.f), fmaxf(a[3] + bi.w, 0.f));
    *(uint2*)(buf + row * kpad + ((((c0 >> 3) ^ (row & 7)) << 3) | (c0 & 7))) = o;
}
__device__ __forceinline__ void stRaw(ushort* buf, int row, int c0, int kpad, f32x4 a, float4 bi) {
    uint2 o;
    o.x = pku(a[0] + bi.x, a[1] + bi.y);
    o.y = pku(a[2] + bi.z, a[3] + bi.w);
    *(uint2*)(buf + row * kpad + ((((c0 >> 3) ^ (row & 7)) << 3) | (c0 & 7))) = o;
}

// ---------------- batchnorm stats ----------------
__global__ __launch_bounds__(256) void bn_stats_kernel(
    const float* __restrict__ x, const float* __restrict__ gamma,
    const float* __restrict__ beta, float* __restrict__ scale, float* __restrict__ bias)
{
    __shared__ float s_sum[256], s_sq[256];
    int p = blockIdx.x, t = threadIdx.x;
    float sum = 0.f, sq = 0.f;
    for (int i = t; i < BB * NN; i += 256) {
        int b = i >> 6, n = i & 63;
        float v = x[b * PP * NN + p * NN + n];
        sum += v; sq += v * v;
    }
    s_sum[t] = sum; s_sq[t] = sq;
    __syncthreads();
    for (int off = 128; off > 0; off >>= 1) {
        if (t < off) { s_sum[t] += s_sum[t + off]; s_sq[t] += s_sq[t + off]; }
        __syncthreads();
    }
    if (t == 0) {
        float inv = 1.f / (float)(BB * NN);
        float mean = s_sum[0] * inv;
        float var  = s_sq[0] * inv - mean * mean;
        float sc   = gamma[p] * rsqrtf(var + EPSBN);
        scale[p] = sc;
        bias[p]  = beta[p] - mean * sc;
    }
}

// ---------------- mega kernel: one block per batch, 8 waves, 2 waves/SIMD ----------------
__global__ __launch_bounds__(512)
__attribute__((amdgpu_waves_per_eu(2, 2)))
void meg_kernel(
    const float* __restrict__ x,
    const float* __restrict__ scl, const float* __restrict__ bia,
    const float* __restrict__ fr1_w, const float* __restrict__ fr1_b,
    const float* __restrict__ fr2_w, const float* __restrict__ fr2_b,
    const float* __restrict__ fr3_w, const float* __restrict__ fr3_b,
    const float* __restrict__ fo1_w, const float* __restrict__ fo1_b,
    const float* __restrict__ fo2_w, const float* __restrict__ fo2_b,
    const float* __restrict__ fo3_w, const float* __restrict__ fo3_b,
    const float* __restrict__ fc1_w, const float* __restrict__ fc1_b,
    const float* __restrict__ fc2_w, const float* __restrict__ fc2_b,
    const float* __restrict__ fc3_w, const float* __restrict__ fc3_b,
    float* __restrict__ out)
{
    __shared__ __align__(16) ushort L[LDSE];

    int b = blockIdx.x, t = threadIdx.x;
    int w = t >> 6, l = t & 63, lx = l & 15, lq = l >> 4;

    // ---- xnT [64][64] (cols 48..63 zero)
    for (int i = t; i < 4096; i += 512) {
        int n = i >> 6, k = i & 63;
        float v = (k < PP) ? x[b * PP * NN + k * NN + n] * scl[k] + bia[k] : 0.f;
        L[XNT2 + sidx(n, k, 64)] = f2b(v);
    }
    // ---- fr1 receiver / sender halves into BIG
    for (int i = t; i < 16384; i += 512) {
        int ch = i >> 6, k = i & 63;
        L[BIGO + sidx(ch, k, 64)]         = f2b((k < PP) ? fr1_w[ch * 96 + k] : 0.f);
        L[BIGO + 16384 + sidx(ch, k, 64)] = f2b((k < PP) ? fr1_w[ch * 96 + PP + k] : 0.f);
    }
    __syncthreads();

    // ---- GEMM1+2 fused: S1R = fr1R.xn + b1, S1S = fr1S.xn  (each wave: 2 m-tiles)
    {
        f32x4 aR[2][4], aS[2][4];
#pragma unroll
        for (int j = 0; j < 2; ++j)
#pragma unroll
            for (int nt = 0; nt < 4; ++nt) { aR[j][nt] = (f32x4){0.f,0.f,0.f,0.f}; aS[j][nt] = (f32x4){0.f,0.f,0.f,0.f}; }
#pragma unroll
        for (int ks = 0; ks < 2; ++ks) {
            bf16x8 Bf[4];
#pragma unroll
            for (int nt = 0; nt < 4; ++nt) Bf[nt] = ldfrag(L + XNT2, nt * 16 + lx, ks * 32 + lq * 8, 64);
#pragma unroll
            for (int j = 0; j < 2; ++j) {
                bf16x8 AfR = ldfrag(L + BIGO,         (2 * w + j) * 16 + lx, ks * 32 + lq * 8, 64);
                bf16x8 AfS = ldfrag(L + BIGO + 16384, (2 * w + j) * 16 + lx, ks * 32 + lq * 8, 64);
#pragma unroll
                for (int nt = 0; nt < 4; ++nt) {
                    aR[j][nt] = MFMA(AfR, Bf[nt], aR[j][nt]);
                    aS[j][nt] = MFMA(AfS, Bf[nt], aS[j][nt]);
                }
            }
        }
        __syncthreads();   // BIG reads done; restage fr2 below
#pragma unroll
        for (int j = 0; j < 2; ++j) {
            int ch0 = (2 * w + j) * 16 + lq * 4;
            float4 bi = *(const float4*)(fr1_b + ch0);
            float4 zb = make_float4(0.f, 0.f, 0.f, 0.f);
#pragma unroll
            for (int nt = 0; nt < 4; ++nt) {
                stRaw(L + S1RO, nt * 16 + lx, ch0, 256, aR[j][nt], bi);
                stRaw(L + S1SO, nt * 16 + lx, ch0, 256, aS[j][nt], zb);
            }
        }
    }
    // ---- fr2 [128][256] -> BIG
    for (int i = t; i < 16384; i += 512) {
        int ch = i >> 7, k2 = (i & 127) * 2;
        float2 v = *(const float2*)(fr2_w + ch * 256 + k2);
        *(unsigned*)(L + BIGO + sidx(ch, k2, 256)) = pku(v.x, v.y);
    }
    // ---- hoist fr3 (B-operand of transposed L3) + biases to registers
    bf16x8 bfw[4][4];
#pragma unroll
    for (int n3 = 0; n3 < 4; ++n3)
#pragma unroll
        for (int ks3 = 0; ks3 < 4; ++ks3) {
            const float* p = fr3_w + (n3 * 16 + lx) * 128 + ks3 * 32 + lq * 8;
            float4 f0 = *(const float4*)p;
            float4 f1 = *(const float4*)(p + 4);
            U8 g;
            g.u[0] = pku(f0.x, f0.y); g.u[1] = pku(f0.z, f0.w);
            g.u[2] = pku(f1.x, f1.y); g.u[3] = pku(f1.z, f1.w);
            bfw[n3][ks3] = g.v;
        }
    float4 b2c[8];
#pragma unroll
    for (int m = 0; m < 8; ++m) b2c[m] = *(const float4*)(fr2_b + m * 16 + lq * 4);
    float b3c[4];
#pragma unroll
    for (int n3 = 0; n3 < 4; ++n3) b3c[n3] = fr3_b[n3 * 16 + lx];
    __syncthreads();

    // ================= phase E: 8 receivers per wave, zero barriers =================
    ushort* a2w = L + A2WO + w * 2048;     // wave-private [16][128]
#pragma unroll 1
    for (int i = 0; i < 8; ++i) {
        int r = w * 8 + i;
        // receiver's L1 pre-act, kept PACKED (32 VGPRs)
        U8 s1rp[8];
#pragma unroll
        for (int ks = 0; ks < 8; ++ks) s1rp[ks].v = ldfrag(L + S1RO, r, ks * 32 + lq * 8, 256);

        float part[4] = {0.f, 0.f, 0.f, 0.f};
#pragma unroll 1
        for (int p = 0; p < 2; ++p) {
            int eA = p * 32 + lx, eB = eA + 16;
            int sA = eA + (eA >= r);
            int sB = eB + (eB >= r); if (sB > 63) sB = 63;   // pad edge 63

            f32x4 acc2[8][2];
#pragma unroll
            for (int m = 0; m < 8; ++m) { acc2[m][0] = (f32x4){0.f,0.f,0.f,0.f}; acc2[m][1] = (f32x4){0.f,0.f,0.f,0.f}; }
#pragma unroll
            for (int ks = 0; ks < 8; ++ks) {
                U8 fa, fb;
                fa.v = ldfrag(L + S1SO, sA, ks * 32 + lq * 8, 256);
                fb.v = ldfrag(L + S1SO, sB, ks * 32 + lq * 8, 256);
                U8 bA, bB;
#pragma unroll
                for (int jj = 0; jj < 4; ++jj) {
                    float r0 = loF(s1rp[ks].u[jj]);
                    float r1 = hiF(s1rp[ks].u[jj]);
                    bA.u[jj] = pku(fmaxf(r0 + loF(fa.u[jj]), 0.f), fmaxf(r1 + hiF(fa.u[jj]), 0.f));
                    bB.u[jj] = pku(fmaxf(r0 + loF(fb.u[jj]), 0.f), fmaxf(r1 + hiF(fb.u[jj]), 0.f));
                }
#pragma unroll
                for (int m = 0; m < 8; ++m) {
                    bf16x8 Af = ldfrag(L + BIGO, m * 16 + lx, ks * 32 + lq * 8, 256);
                    acc2[m][0] = MFMA(Af, bA.v, acc2[m][0]);
                    acc2[m][1] = MFMA(Af, bB.v, acc2[m][1]);
                }
            }
#pragma unroll
            for (int cc = 0; cc < 2; ++cc) {
#pragma unroll
                for (int m = 0; m < 8; ++m)
                    stAct(a2w, lx, m * 16 + lq * 4, 128, acc2[m][cc], b2c[m]);
                f32x4 acc3[4];
#pragma unroll
                for (int n3 = 0; n3 < 4; ++n3) acc3[n3] = (f32x4){0.f,0.f,0.f,0.f};
#pragma unroll
                for (int ks3 = 0; ks3 < 4; ++ks3) {
                    bf16x8 af = ldfrag(a2w, lx, ks3 * 32 + lq * 8, 128);
#pragma unroll
                    for (int n3 = 0; n3 < 4; ++n3) acc3[n3] = MFMA(af, bfw[n3][ks3], acc3[n3]);
                }
                bool mpad = (p == 1) && (cc == 1) && (lq == 3);
#pragma unroll
                for (int n3 = 0; n3 < 4; ++n3) {
                    float bv = b3c[n3];
                    float s = fmaxf(acc3[n3][0] + bv, 0.f) + fmaxf(acc3[n3][1] + bv, 0.f)
                            + fmaxf(acc3[n3][2] + bv, 0.f);
                    float s3 = fmaxf(acc3[n3][3] + bv, 0.f);
                    part[n3] += s + (mpad ? 0.f : s3);
                }
            }
        }
#pragma unroll
        for (int n3 = 0; n3 < 4; ++n3) {
            part[n3] += __shfl_xor(part[n3], 16, 64);
            part[n3] += __shfl_xor(part[n3], 32, 64);
        }
        if (lq == 0) {
#pragma unroll
            for (int n3 = 0; n3 < 4; ++n3)
                L[S1RO + sidx(r, n3 * 16 + lx, 256)] = f2b(part[n3]);
        }
    }
    __syncthreads();

    // ================= phase N =================
    // fo1 -> BIG [256][128] (cols 0..63 ebar part, 64..111 xn part)
    for (int i = t; i < 32768; i += 512) {
        int ch = i >> 7, k = i & 127;
        float v = 0.f;
        if (k < 64)       v = fo1_w[ch * 112 + PP + k];
        else if (k < 112) v = fo1_w[ch * 112 + (k - 64)];
        L[BIGO + sidx(ch, k, 128)] = f2b(v);
    }
    // restage xnT (clobbered by waves 4..7 a2w in phase E)
    for (int i = t; i < 4096; i += 512) {
        int n = i >> 6, k = i & 63;
        float v = (k < PP) ? x[b * PP * NN + k * NN + n] * scl[k] + bia[k] : 0.f;
        L[XNT2 + sidx(n, k, 64)] = f2b(v);
    }
    __syncthreads();

    // L1N: M=256 (wave: 2 m-tiles), N=64 nodes, K=128 (ks 0,1 ebar from S1RO; ks 2,3 from XNT2)
    {
        f32x4 accN[2][4];
#pragma unroll
        for (int j = 0; j < 2; ++j)
#pragma unroll
            for (int nt = 0; nt < 4; ++nt) accN[j][nt] = (f32x4){0.f,0.f,0.f,0.f};
#pragma unroll
        for (int ks = 0; ks < 4; ++ks) {
            bf16x8 Bf[4];
#pragma unroll
            for (int nt = 0; nt < 4; ++nt)
                Bf[nt] = (ks < 2) ? ldfrag(L + S1RO, nt * 16 + lx, ks * 32 + lq * 8, 256)
                                  : ldfrag(L + XNT2, nt * 16 + lx, (ks - 2) * 32 + lq * 8, 64);
#pragma unroll
            for (int j = 0; j < 2; ++j) {
                bf16x8 Af = ldfrag(L + BIGO, (2 * w + j) * 16 + lx, ks * 32 + lq * 8, 128);
#pragma unroll
                for (int nt = 0; nt < 4; ++nt) accN[j][nt] = MFMA(Af, Bf[nt], accN[j][nt]);
            }
        }
        __syncthreads();   // BIG/S1RO/XNT2 reads done
#pragma unroll
        for (int j = 0; j < 2; ++j) {
            int ch0 = (2 * w + j) * 16 + lq * 4;
            float4 bi = *(const float4*)(fo1_b + ch0);
#pragma unroll
            for (int nt = 0; nt < 4; ++nt)
                stAct(L + S1SO, nt * 16 + lx, ch0, 256, accN[j][nt], bi);
        }
    }
    // fo2 -> BIG [128][256]; fo3 -> S1RO [64][128]
    for (int i = t; i < 16384; i += 512) {
        int ch = i >> 7, k2 = (i & 127) * 2;
        float2 v = *(const float2*)(fo2_w + ch * 256 + k2);
        *(unsigned*)(L + BIGO + sidx(ch, k2, 256)) = pku(v.x, v.y);
    }
    for (int i = t; i < 4096; i += 512) {
        int ch = i >> 6, k2 = (i & 63) * 2;
        float2 v = *(const float2*)(fo3_w + ch * 128 + k2);
        *(unsigned*)(L + S1RO + sidx(ch, k2, 128)) = pku(v.x, v.y);
    }
    __syncthreads();

    // L2N: M=128 (wave: m-tile w), N=64, K=256 -> act2N @ A2WO [64][128]
    {
        f32x4 a2N[4];
#pragma unroll
        for (int nt = 0; nt < 4; ++nt) a2N[nt] = (f32x4){0.f,0.f,0.f,0.f};
#pragma unroll
        for (int ks = 0; ks < 8; ++ks) {
            bf16x8 Bf[4];
#pragma unroll
            for (int nt = 0; nt < 4; ++nt) Bf[nt] = ldfrag(L + S1SO, nt * 16 + lx, ks * 32 + lq * 8, 256);
            bf16x8 Af = ldfrag(L + BIGO, w * 16 + lx, ks * 32 + lq * 8, 256);
#pragma unroll
            for (int nt = 0; nt < 4; ++nt) a2N[nt] = MFMA(Af, Bf[nt], a2N[nt]);
        }
        int ch0 = w * 16 + lq * 4;
        float4 bi = *(const float4*)(fo2_b + ch0);
#pragma unroll
        for (int nt = 0; nt < 4; ++nt)
            stAct(L + A2WO, nt * 16 + lx, ch0, 128, a2N[nt], bi);
    }
    __syncthreads();

    // L3N: M=64 (fo3 ch), N=64 nodes, K=128 (waves 0..3); relu+bias, sum over nodes
    if (w < 4) {
        f32x4 a3N[4];
#pragma unroll
        for (int nt = 0; nt < 4; ++nt) a3N[nt] = (f32x4){0.f,0.f,0.f,0.f};
#pragma unroll
        for (int ks3 = 0; ks3 < 4; ++ks3) {
            bf16x8 Af = ldfrag(L + S1RO, 16 * w + lx, ks3 * 32 + lq * 8, 128);
#pragma unroll
            for (int nt = 0; nt < 4; ++nt) {
                bf16x8 Bf = ldfrag(L + A2WO, nt * 16 + lx, ks3 * 32 + lq * 8, 128);
                a3N[nt] = MFMA(Af, Bf, a3N[nt]);
            }
        }
        float4 b3 = *(const float4*)(fo3_b + 16 * w + lq * 4);
        float o0 = 0.f, o1 = 0.f, o2 = 0.f, o3 = 0.f;
#pragma unroll
        for (int nt = 0; nt < 4; ++nt) {
            o0 += fmaxf(a3N[nt][0] + b3.x, 0.f);
            o1 += fmaxf(a3N[nt][1] + b3.y, 0.f);
            o2 += fmaxf(a3N[nt][2] + b3.z, 0.f);
            o3 += fmaxf(a3N[nt][3] + b3.w, 0.f);
        }
#pragma unroll
        for (int off = 8; off >= 1; off >>= 1) {
            o0 += __shfl_xor(o0, off, 16);
            o1 += __shfl_xor(o1, off, 16);
            o2 += __shfl_xor(o2, off, 16);
            o3 += __shfl_xor(o3, off, 16);
        }
        if (lx == 0) {
            float* red = (float*)(L + REDO);
            *(float4*)&red[16 * w + lq * 4] = make_float4(o0, o1, o2, o3);
        }
    }
    __syncthreads();

    // ---- final FCs (fp32)
    {
        float* red = (float*)(L + REDO);
        float* h1  = red + 64;
        float* h2  = red + 96;
        if (t < 25) {
            float s = fc1_b[t];
            for (int k = 0; k < 64; ++k) s += fc1_w[t * 64 + k] * red[k];
            h1[t] = s;
        }
        __syncthreads();
        if (t < 15) {
            float s = fc2_b[t];
            for (int k = 0; k < 25; ++k) s += fc2_w[t * 25 + k] * h1[k];
            h2[t] = s;
        }
        __syncthreads();
        if (t < 5) {
            float s = fc3_b[t];
            for (int k = 0; k < 15; ++k) s += fc3_w[t * 15 + k] * h2[k];
            out[b * 5 + t] = s;
        }
    }
}

extern "C" void kernel_launch(void* const* d_in, const int* in_sizes, int n_in,
                              void* d_out, int out_size, void* d_ws, size_t ws_size,
                              hipStream_t stream)
{
    const float* x        = (const float*)d_in[0];
    const float* bn_gamma = (const float*)d_in[3];
    const float* bn_beta  = (const float*)d_in[4];
    const float* fr1_w = (const float*)d_in[5];
    const float* fr1_b = (const float*)d_in[6];
    const float* fr2_w = (const float*)d_in[7];
    const float* fr2_b = (const float*)d_in[8];
    const float* fr3_w = (const float*)d_in[9];
    const float* fr3_b = (const float*)d_in[10];
    const float* fo1_w = (const float*)d_in[11];
    const float* fo1_b = (const float*)d_in[12];
    const float* fo2_w = (const float*)d_in[13];
    const float* fo2_b = (const float*)d_in[14];
    const float* fo3_w = (const float*)d_in[15];
    const float* fo3_b = (const float*)d_in[16];
    const float* fc1_w = (const float*)d_in[17];
    const float* fc1_b = (const float*)d_in[18];
    const float* fc2_w = (const float*)d_in[19];
    const float* fc2_b = (const float*)d_in[20];
    const float* fc3_w = (const float*)d_in[21];
    const float* fc3_b = (const float*)d_in[22];

    float* ws    = (float*)d_ws;
    float* scale = ws;
    float* bias  = ws + 64;
    float* out   = (float*)d_out;

    bn_stats_kernel<<<dim3(PP), dim3(256), 0, stream>>>(x, bn_gamma, bn_beta, scale, bias);
    meg_kernel<<<dim3(BB), dim3(512), 0, stream>>>(
        x, scale, bias,
        fr1_w, fr1_b, fr2_w, fr2_b, fr3_w, fr3_b,
        fo1_w, fo1_b, fo2_w, fo2_b, fo3_w, fo3_b,
        fc1_w, fc1_b, fc2_w, fc2_b, fc3_w, fc3_b, out);
}